// Round 3
// baseline (167.351 us; speedup 1.0000x reference)
//
#include <hip/hip_runtime.h>
#include <hip/hip_bf16.h>

// DenseLayer: out[i] = (x_i @ w == 0) ? 0 : (x_i^2 @ w) / (x_i @ w)
// N = 1,000,000 rows, E = 256 cols, fp32.
//
// NUMERICS IS THE WHOLE GAME HERE. The harness compares against numpy's
// fp32 BLAS (OpenBLAS sgemv). At the worst rows s ~ 1e-5 while num ~ 20, so
// out ~ 1e6 and d(out)/d(s) ~ num/s^2 ~ 1e11: one ulp of summation-order
// difference in s moves the output by ~1e5. Evidence: our fp64 EXACT kernel
// scored absmax 5.2e6 — the true value itself is 5e6 from the fp32 ref.
// The jax-vs-np threshold (1.37e5) is only achievable if both use the same
// main summation: 8-wide AVX2 FMA, single accumulator per output, k stride 8
// (they differ only in the final horizontal bracket). We therefore replicate
// OpenBLAS's order bit-exactly:
//   acc_j (j=0..7):  acc_j = fma(x[8k+j], w[8k+j], acc_j),  k = 0..31
//   horizontal (vextract+add, vhaddps, vhaddps):
//       s = ((s0+s4)+(s1+s5)) + ((s2+s6)+(s3+s7))
// num: xx = RN(x*x) elementwise, then the identical chain. fp32 IEEE divide.
//
// Mapping: 8 lanes per row; lane j IS SIMD slot j. Shuffle masks 4,1,2 (in
// that order) reproduce the hadd bracket bit-exactly (fp add is commutative
// in RN, so self+partner order is safe).

__global__ __launch_bounds__(256) void DenseLayer_32899449487452_kernel(
    const float* __restrict__ x,
    const float* __restrict__ w,
    float* __restrict__ out,
    int nrows)
{
    const long long gtid = (long long)blockIdx.x * blockDim.x + threadIdx.x;
    const int row = (int)(gtid >> 3);      // 8 lanes per row
    const int j   = threadIdx.x & 7;       // SIMD slot index
    if (row >= nrows) return;

    const float* xr = x + (size_t)row * 256;

    float s = 0.0f, num = 0.0f;
    #pragma unroll
    for (int k = 0; k < 32; ++k) {
        const float xv = xr[k * 8 + j];
        const float wv = w[k * 8 + j];
        s   = fmaf(xv, wv, s);             // single fused-FMA chain, stride 8
        num = fmaf(xv * xv, wv, num);      // RN(x^2) then same chain
    }

    // OpenBLAS horizontal reduction bracket:
    //   step 1 (extractf128 + addps): s_j + s_{j^4}
    //   step 2 (vhaddps):             pairs (0,1),(2,3)
    //   step 3 (vhaddps):             pair  (01,23)
    s   += __shfl_xor(s,   4, 64);   num += __shfl_xor(num, 4, 64);
    s   += __shfl_xor(s,   1, 64);   num += __shfl_xor(num, 1, 64);
    s   += __shfl_xor(s,   2, 64);   num += __shfl_xor(num, 2, 64);

    if (j == 0) {
        out[row] = (s == 0.0f) ? 0.0f : num / s;   // IEEE fp32 divide
    }
}

extern "C" void kernel_launch(void* const* d_in, const int* in_sizes, int n_in,
                              void* d_out, int out_size, void* d_ws, size_t ws_size,
                              hipStream_t stream)
{
    const float* x = (const float*)d_in[0];
    const float* w = (const float*)d_in[1];
    float* out = (float*)d_out;

    const int nrows = in_sizes[0] / 256;            // 1,000,000
    const long long threads = (long long)nrows * 8; // 8 lanes per row
    const int block = 256;
    const int grid = (int)((threads + block - 1) / block);

    DenseLayer_32899449487452_kernel<<<grid, block, 0, stream>>>(x, w, out, nrows);
}